// Round 6
// baseline (57.537 us; speedup 1.0000x reference)
//
#include <hip/hip_runtime.h>

#define DIM 32
#define KK 64
#define WPB 4
#define WIH_STRIDE 144          // packed W_ih row: 128B data + 16 pad
#define WHH_STRIDE 80           // packed W_hh row: 64B data + 16 pad
#define REL_STRIDE 80           // packed relation row: 64B data + 16 pad
#define LDS_WIH (32 * WIH_STRIDE)
#define LDS_WHH (32 * WHH_STRIDE)
#define LDS_REL (64 * REL_STRIDE)

typedef short bf16x8 __attribute__((ext_vector_type(8)));
typedef float f32x16 __attribute__((ext_vector_type(16)));
typedef unsigned int u32x4 __attribute__((ext_vector_type(4)));

__device__ __forceinline__ float rcp_fast(float x) { return __builtin_amdgcn_rcpf(x); }

// tanh(x) = 1 - 2/(exp(2x)+1); graceful at +-inf
__device__ __forceinline__ float tanh_fast(float x) {
    float t = __expf(2.0f * x);
    return 1.0f - 2.0f * rcp_fast(t + 1.0f);
}

// pack two f32 -> one dword of 2 bf16 (truncation) via v_perm_b32
__device__ __forceinline__ unsigned pk2(float lo, float hi) {
    return __builtin_amdgcn_perm(__builtin_bit_cast(unsigned, hi),
                                 __builtin_bit_cast(unsigned, lo), 0x07060302u);
}

// unpack bf16 pair dword -> floats
__device__ __forceinline__ float lo16(unsigned u) { return __builtin_bit_cast(float, u << 16); }
__device__ __forceinline__ float hi16(unsigned u) { return __builtin_bit_cast(float, u & 0xffff0000u); }

__device__ __forceinline__ bf16x8 pack8(float4 a, float4 b) {
    u32x4 u;
    u[0] = pk2(a.x, a.y); u[1] = pk2(a.z, a.w);
    u[2] = pk2(b.x, b.y); u[3] = pk2(b.z, b.w);
    return __builtin_bit_cast(bf16x8, u);
}

__device__ __forceinline__ float dot4(float4 a, float4 b) {
    float s = a.x * b.x;
    s = fmaf(a.y, b.y, s); s = fmaf(a.z, b.z, s); s = fmaf(a.w, b.w, s);
    return s;
}

// ---- K0: f32 entity table -> bf16 table (streaming) ----
__global__ __launch_bounds__(256) void cvt_bf16(
    const float* __restrict__ in, unsigned* __restrict__ outp, const long n8)
{
    long i = (long)blockIdx.x * 256 + threadIdx.x;
    const long stride = (long)gridDim.x * 256;
    for (; i < n8; i += stride) {
        const float4 a = ((const float4*)in)[2 * i];
        const float4 c = ((const float4*)in)[2 * i + 1];
        u32x4 u;
        u[0] = pk2(a.x, a.y); u[1] = pk2(a.z, a.w);
        u[2] = pk2(c.x, c.y); u[3] = pk2(c.z, c.w);
        ((u32x4*)outp)[i] = u;
    }
}

// ---- K1: fused per-b wave, all gathers upfront ----
template <bool BF16>
__global__ __launch_bounds__(256, 2) void ripple_fused(
    const int* __restrict__ users,
    const int* __restrict__ items,
    const int* __restrict__ hop0_items,
    const int* __restrict__ heads,
    const int* __restrict__ relations,
    const int* __restrict__ tails,
    const float* __restrict__ entity_emb,
    const float* __restrict__ relation_emb,
    const float* __restrict__ rec_user_emb,
    const float* __restrict__ rec_item_emb,
    const float* __restrict__ W_ih,
    const float* __restrict__ W_hh,
    const float* __restrict__ b_ih,
    const float* __restrict__ b_hh,
    const unsigned* __restrict__ tabbf,     // bf16 entity table (u32 pairs); null in f32 mode
    float* __restrict__ out,
    const int B)
{
    __shared__ __align__(16) unsigned char lds[LDS_WIH + LDS_WHH + LDS_REL + 256];
    unsigned char* wihL = lds;
    unsigned char* whhL = lds + LDS_WIH;
    unsigned char* relL = lds + LDS_WIH + LDS_WHH;
    float* rrL = (float*)(lds + LDS_WIH + LDS_WHH + LDS_REL);

    const int tid = threadIdx.x;

    // ---- stage packed bf16 weight + relation images (per block) ----
    #pragma unroll
    for (int c = 0; c < 4; ++c) {
        int i = tid + 256 * c;              // 0..1023 (W_ih: 32 rows x 32 dwords)
        int row = i >> 5, dw = i & 31;
        *(unsigned*)(wihL + row * WIH_STRIDE + dw * 4) =
            pk2(W_ih[row * 64 + 2 * dw], W_ih[row * 64 + 2 * dw + 1]);
    }
    #pragma unroll
    for (int c = 0; c < 2; ++c) {
        int i = tid + 256 * c;              // 0..511 (W_hh: 32 rows x 16 dwords)
        int row = i >> 4, dw = i & 15;
        *(unsigned*)(whhL + row * WHH_STRIDE + dw * 4) =
            pk2(W_hh[row * 32 + 2 * dw], W_hh[row * 32 + 2 * dw + 1]);
    }
    #pragma unroll
    for (int c = 0; c < 4; ++c) {
        int i = tid + 256 * c;              // 0..1023 (rel: 64 rows x 16 dwords)
        int row = i >> 4, dw = i & 15;
        *(unsigned*)(relL + row * REL_STRIDE + dw * 4) =
            pk2(relation_emb[row * 32 + 2 * dw], relation_emb[row * 32 + 2 * dw + 1]);
    }
    if (tid < 64) {                          // rr[r] = r . r (exact f32)
        float s = 0.0f;
        #pragma unroll
        for (int e = 0; e < DIM; ++e) {
            float v = relation_emb[tid * DIM + e];
            s = fmaf(v, v, s);
        }
        rrL[tid] = s;
    }
    __syncthreads();

    const int wv   = tid >> 6;
    const int lane = tid & 63;
    const int h5   = lane >> 5;
    const int p    = lane & 31;
    const int bb_  = blockIdx.x * WPB + wv;
    if (bb_ >= B) return;
    const int b = __builtin_amdgcn_readfirstlane(bb_);

    // ---- ALL index loads upfront (coalesced) ----
    const int i0A = hop0_items[b * KK + p];
    const int i0B = hop0_items[b * KK + 32 + p];
    int ihA[2], ihB[2], irA[2], irB[2], itA[2], itB[2];
    #pragma unroll
    for (int l = 0; l < 2; ++l) {
        const int base = (l * B + b) * KK;
        ihA[l] = heads[base + p];     ihB[l] = heads[base + 32 + p];
        irA[l] = relations[base + p]; irB[l] = relations[base + 32 + p];
        itA[l] = tails[base + p];     itB[l] = tails[base + 32 + p];
    }

    // ---- ALL entity gathers upfront (bf16 path: direct B-frag layout) ----
    u32x4 g0[2][2], gH[2][2][2], gT[2][2][2];   // [nt][kt], [l][nt][kt]
    if constexpr (BF16) {
        const u32x4* T4 = (const u32x4*)tabbf;
        #pragma unroll
        for (int kt = 0; kt < 2; ++kt) {
            g0[0][kt] = T4[(size_t)i0A * 4 + 2 * kt + h5];
            g0[1][kt] = T4[(size_t)i0B * 4 + 2 * kt + h5];
        }
        #pragma unroll
        for (int l = 0; l < 2; ++l)
            #pragma unroll
            for (int kt = 0; kt < 2; ++kt) {
                gH[l][0][kt] = T4[(size_t)ihA[l] * 4 + 2 * kt + h5];
                gH[l][1][kt] = T4[(size_t)ihB[l] * 4 + 2 * kt + h5];
                gT[l][0][kt] = T4[(size_t)itA[l] * 4 + 2 * kt + h5];
                gT[l][1][kt] = T4[(size_t)itB[l] * 4 + 2 * kt + h5];
            }
    }

    // ---- uniform q, bias (s_load) + user.q ----
    const int it = __builtin_amdgcn_readfirstlane(items[b]);
    const int uu = __builtin_amdgcn_readfirstlane(users[b]);
    float qu[DIM], bu[DIM];
    #pragma unroll
    for (int d = 0; d < DIM; ++d) {
        qu[d] = entity_emb[(size_t)it * DIM + d] + rec_item_emb[(size_t)it * DIM + d];
        bu[d] = b_ih[d] + b_hh[d];
    }
    float up = 0.0f;
    #pragma unroll
    for (int d = 0; d < DIM; ++d)
        up = fmaf(rec_user_emb[(size_t)uu * DIM + d], qu[d], up);

    // lane-selected views (static indices, cndmask from SGPR)
    float qfa[8], qfb[8];                    // elems [8h5+j], [16+8h5+j]
    #pragma unroll
    for (int j = 0; j < 8; ++j) {
        qfa[j] = h5 ? qu[8 + j]  : qu[j];
        qfb[j] = h5 ? qu[24 + j] : qu[16 + j];
    }
    float qf[16], bv[16];                    // C/D-layout rows d = 8Q + 4h5 + j
    #pragma unroll
    for (int Q = 0; Q < 4; ++Q)
        #pragma unroll
        for (int j = 0; j < 4; ++j) {
            qf[4*Q+j] = h5 ? qu[8*Q + 4 + j] : qu[8*Q + j];
            bv[4*Q+j] = h5 ? bu[8*Q + 4 + j] : bu[8*Q + j];
        }

    // ---- hop-0 dot ----
    float part = 0.0f;
    if constexpr (BF16) {
        #pragma unroll
        for (int nt = 0; nt < 2; ++nt)
            #pragma unroll
            for (int j = 0; j < 4; ++j) {
                part = fmaf(lo16(g0[nt][0][j]), qfa[2*j],     part);
                part = fmaf(hi16(g0[nt][0][j]), qfa[2*j + 1], part);
                part = fmaf(lo16(g0[nt][1][j]), qfb[2*j],     part);
                part = fmaf(hi16(g0[nt][1][j]), qfb[2*j + 1], part);
            }
    } else {
        const float* a0  = entity_emb + (size_t)i0A * DIM + 8 * h5;
        const float* b0p = entity_emb + (size_t)i0B * DIM + 8 * h5;
        float4 vA0 = *(const float4*)(a0);      float4 vA1 = *(const float4*)(a0 + 4);
        float4 vA2 = *(const float4*)(a0 + 16); float4 vA3 = *(const float4*)(a0 + 20);
        float4 vB0 = *(const float4*)(b0p);      float4 vB1 = *(const float4*)(b0p + 4);
        float4 vB2 = *(const float4*)(b0p + 16); float4 vB3 = *(const float4*)(b0p + 20);
        float4 c0a = make_float4(qfa[0], qfa[1], qfa[2], qfa[3]);
        float4 c0b = make_float4(qfa[4], qfa[5], qfa[6], qfa[7]);
        float4 c1a = make_float4(qfb[0], qfb[1], qfb[2], qfb[3]);
        float4 c1b = make_float4(qfb[4], qfb[5], qfb[6], qfb[7]);
        part = dot4(vA0, c0a) + dot4(vA1, c0b) + dot4(vA2, c1a) + dot4(vA3, c1b)
             + dot4(vB0, c0a) + dot4(vB1, c0b) + dot4(vB2, c1a) + dot4(vB3, c1b);
    }
    #pragma unroll
    for (int m = 1; m <= 32; m <<= 1) part += __shfl_xor(part, m, 64);

    float tot = part + up;

    // ---- weight frags from block LDS ----
    bf16x8 wihF[4], whhF[2];
    #pragma unroll
    for (int kt = 0; kt < 4; ++kt)
        wihF[kt] = __builtin_bit_cast(bf16x8,
            *(const u32x4*)(wihL + p * WIH_STRIDE + kt * 32 + h5 * 16));
    #pragma unroll
    for (int kt = 0; kt < 2; ++kt)
        whhF[kt] = __builtin_bit_cast(bf16x8,
            *(const u32x4*)(whhL + p * WHH_STRIDE + kt * 32 + h5 * 16));

    // ---- hops ----
    #pragma unroll
    for (int l = 0; l < 2; ++l) {
        bf16x8 hfr[2][2], tfr[2][2];
        float scA = 0.0f, scB = 0.0f;
        if constexpr (BF16) {
            #pragma unroll
            for (int kt = 0; kt < 2; ++kt)
                #pragma unroll
                for (int j = 0; j < 4; ++j) {
                    scA = fmaf(lo16(gH[l][0][kt][j]), lo16(gT[l][0][kt][j]), scA);
                    scA = fmaf(hi16(gH[l][0][kt][j]), hi16(gT[l][0][kt][j]), scA);
                    scB = fmaf(lo16(gH[l][1][kt][j]), lo16(gT[l][1][kt][j]), scB);
                    scB = fmaf(hi16(gH[l][1][kt][j]), hi16(gT[l][1][kt][j]), scB);
                }
            #pragma unroll
            for (int nt = 0; nt < 2; ++nt)
                #pragma unroll
                for (int kt = 0; kt < 2; ++kt) {
                    hfr[nt][kt] = __builtin_bit_cast(bf16x8, gH[l][nt][kt]);
                    tfr[nt][kt] = __builtin_bit_cast(bf16x8, gT[l][nt][kt]);
                }
        } else {
            float4 fh[8], ft[8];
            {
                const float* a = entity_emb + (size_t)ihA[l] * DIM + 8 * h5;
                const float* c = entity_emb + (size_t)ihB[l] * DIM + 8 * h5;
                fh[0] = *(const float4*)(a);      fh[1] = *(const float4*)(a + 4);
                fh[2] = *(const float4*)(a + 16); fh[3] = *(const float4*)(a + 20);
                fh[4] = *(const float4*)(c);      fh[5] = *(const float4*)(c + 4);
                fh[6] = *(const float4*)(c + 16); fh[7] = *(const float4*)(c + 20);
            }
            {
                const float* a = entity_emb + (size_t)itA[l] * DIM + 8 * h5;
                const float* c = entity_emb + (size_t)itB[l] * DIM + 8 * h5;
                ft[0] = *(const float4*)(a);      ft[1] = *(const float4*)(a + 4);
                ft[2] = *(const float4*)(a + 16); ft[3] = *(const float4*)(a + 20);
                ft[4] = *(const float4*)(c);      ft[5] = *(const float4*)(c + 4);
                ft[6] = *(const float4*)(c + 16); ft[7] = *(const float4*)(c + 20);
            }
            #pragma unroll
            for (int i = 0; i < 4; ++i) scA += dot4(fh[i], ft[i]);
            #pragma unroll
            for (int i = 4; i < 8; ++i) scB += dot4(fh[i], ft[i]);
            #pragma unroll
            for (int nt = 0; nt < 2; ++nt)
                #pragma unroll
                for (int kt = 0; kt < 2; ++kt) {
                    hfr[nt][kt] = pack8(fh[nt*4 + kt*2], fh[nt*4 + kt*2 + 1]);
                    tfr[nt][kt] = pack8(ft[nt*4 + kt*2], ft[nt*4 + kt*2 + 1]);
                }
        }

        // relation frags + rr from LDS
        bf16x8 rfr[2][2];
        #pragma unroll
        for (int kt = 0; kt < 2; ++kt) {
            rfr[0][kt] = __builtin_bit_cast(bf16x8,
                *(const u32x4*)(relL + irA[l] * REL_STRIDE + kt * 32 + h5 * 16));
            rfr[1][kt] = __builtin_bit_cast(bf16x8,
                *(const u32x4*)(relL + irB[l] * REL_STRIDE + kt * 32 + h5 * 16));
        }
        const float rrA = rrL[irA[l]];
        const float rrB = rrL[irB[l]];

        // ---- MFMA chain ----
        f32x16 accA[2], accB[2];
        {
            f32x16 bias_v;
            #pragma unroll
            for (int j = 0; j < 16; ++j) bias_v[j] = bv[j];
            accA[0] = bias_v; accA[1] = bias_v;
        }
        #pragma unroll
        for (int nt = 0; nt < 2; ++nt)
            #pragma unroll
            for (int kt = 0; kt < 2; ++kt)
                accA[nt] = __builtin_amdgcn_mfma_f32_32x32x16_bf16(
                    wihF[2 + kt], rfr[nt][kt], accA[nt], 0, 0, 0);     // C_r
        accB[0] = accA[0]; accB[1] = accA[1];
        #pragma unroll
        for (int nt = 0; nt < 2; ++nt)
            #pragma unroll
            for (int kt = 0; kt < 2; ++kt)
                accB[nt] = __builtin_amdgcn_mfma_f32_32x32x16_bf16(
                    wihF[kt], hfr[nt][kt], accB[nt], 0, 0, 0);         // SH
        #pragma unroll
        for (int nt = 0; nt < 2; ++nt)
            #pragma unroll
            for (int kt = 0; kt < 2; ++kt)
                accA[nt] = __builtin_amdgcn_mfma_f32_32x32x16_bf16(
                    wihF[kt], tfr[nt][kt], accA[nt], 0, 0, 0);         // ST

        // h1 = tanh(SH): in-register C/D -> B-frag transpose via shfl_xor(32)
        unsigned dwA[2][4], dwB[2][4];
        #pragma unroll
        for (int nt = 0; nt < 2; ++nt)
            #pragma unroll
            for (int Q = 0; Q < 4; ++Q) {
                dwA[nt][Q] = pk2(tanh_fast(accB[nt][4*Q+0]), tanh_fast(accB[nt][4*Q+1]));
                dwB[nt][Q] = pk2(tanh_fast(accB[nt][4*Q+2]), tanh_fast(accB[nt][4*Q+3]));
            }
        #pragma unroll
        for (int nt = 0; nt < 2; ++nt)
            #pragma unroll
            for (int kt = 0; kt < 2; ++kt) {
                const unsigned ownA = h5 ? dwA[nt][2*kt+1] : dwA[nt][2*kt];
                const unsigned ownB = h5 ? dwB[nt][2*kt+1] : dwB[nt][2*kt];
                const unsigned sndA = h5 ? dwA[nt][2*kt]   : dwA[nt][2*kt+1];
                const unsigned sndB = h5 ? dwB[nt][2*kt]   : dwB[nt][2*kt+1];
                const unsigned rcvA = __shfl_xor(sndA, 32, 64);
                const unsigned rcvB = __shfl_xor(sndB, 32, 64);
                u32x4 u;
                u[0] = h5 ? rcvA : ownA;
                u[1] = h5 ? rcvB : ownB;
                u[2] = h5 ? ownA : rcvA;
                u[3] = h5 ? ownB : rcvB;
                accA[nt] = __builtin_amdgcn_mfma_f32_32x32x16_bf16(
                    whhF[kt], __builtin_bit_cast(bf16x8, u), accA[nt], 0, 0, 0);  // PRE
            }

        // h2 = tanh(PRE); dots; softmax-weighted sum
        float sA = scA + __shfl_xor(scA, 32, 64);
        float sB = scB + __shfl_xor(scB, 32, 64);
        const float e0 = __expf(sA + rrA);
        const float e1 = __expf(sB + rrB);

        float sd0 = 0.0f, sd1 = 0.0f;
        #pragma unroll
        for (int j = 0; j < 16; ++j) sd0 = fmaf(tanh_fast(accA[0][j]), qf[j], sd0);
        #pragma unroll
        for (int j = 0; j < 16; ++j) sd1 = fmaf(tanh_fast(accA[1][j]), qf[j], sd1);
        sd0 += __shfl_xor(sd0, 32, 64);
        sd1 += __shfl_xor(sd1, 32, 64);

        float num = e0 * sd0 + e1 * sd1;
        float den = e0 + e1;
        #pragma unroll
        for (int m = 1; m <= 16; m <<= 1) {
            num += __shfl_xor(num, m, 64);
            den += __shfl_xor(den, m, 64);
        }
        tot += num * rcp_fast(den);
    }

    if (lane == 0) out[b] = rcp_fast(1.0f + __expf(-tot));
}

extern "C" void kernel_launch(void* const* d_in, const int* in_sizes, int n_in,
                              void* d_out, int out_size, void* d_ws, size_t ws_size,
                              hipStream_t stream)
{
    const int* users = (const int*)d_in[0];
    const int* items = (const int*)d_in[1];
    const int* hop0  = (const int*)d_in[2];
    const int* heads = (const int*)d_in[3];
    const int* rels  = (const int*)d_in[4];
    const int* tails = (const int*)d_in[5];
    const float* entity_emb   = (const float*)d_in[6];
    const float* relation_emb = (const float*)d_in[7];
    const float* rec_user_emb = (const float*)d_in[8];
    const float* rec_item_emb = (const float*)d_in[9];
    const float* W_ih = (const float*)d_in[10];
    const float* W_hh = (const float*)d_in[11];
    const float* b_ih = (const float*)d_in[12];
    const float* b_hh = (const float*)d_in[13];
    float* out = (float*)d_out;

    const int B = in_sizes[0];
    const long nent_elems = (long)in_sizes[6];            // N_ENTITY * DIM
    const size_t need = (size_t)nent_elems * 2;           // bf16 table bytes
    const int blocks1 = (B + WPB - 1) / WPB;

    if (ws_size >= need) {
        hipLaunchKernelGGL(cvt_bf16, dim3(2048), dim3(256), 0, stream,
                           entity_emb, (unsigned*)d_ws, nent_elems / 8);
        hipLaunchKernelGGL((ripple_fused<true>), dim3(blocks1), dim3(256), 0, stream,
                           users, items, hop0, heads, rels, tails,
                           entity_emb, relation_emb, rec_user_emb, rec_item_emb,
                           W_ih, W_hh, b_ih, b_hh,
                           (const unsigned*)d_ws, out, B);
    } else {
        hipLaunchKernelGGL((ripple_fused<false>), dim3(blocks1), dim3(256), 0, stream,
                           users, items, hop0, heads, rels, tails,
                           entity_emb, relation_emb, rec_user_emb, rec_item_emb,
                           W_ih, W_hh, b_ih, b_hh,
                           (const unsigned*)nullptr, out, B);
    }
}

// Round 7
// 49.332 us; speedup vs baseline: 1.1663x; 1.1663x over previous
//
#include <hip/hip_runtime.h>

#define DIM 32
#define KK 64
#define WPB 4
#define WIH_STRIDE 144          // packed W_ih row: 128B data + 16 pad
#define WHH_STRIDE 80           // packed W_hh row: 64B data + 16 pad
#define REL_STRIDE 80           // packed relation row: 64B data + 16 pad
#define LDS_WIH (32 * WIH_STRIDE)
#define LDS_WHH (32 * WHH_STRIDE)
#define LDS_REL (64 * REL_STRIDE)

typedef short bf16x8 __attribute__((ext_vector_type(8)));
typedef float f32x16 __attribute__((ext_vector_type(16)));
typedef unsigned int u32x4 __attribute__((ext_vector_type(4)));

__device__ __forceinline__ float rcp_fast(float x) { return __builtin_amdgcn_rcpf(x); }

// tanh(x) = 1 - 2/(exp(2x)+1); graceful at +-inf
__device__ __forceinline__ float tanh_fast(float x) {
    float t = __expf(2.0f * x);
    return 1.0f - 2.0f * rcp_fast(t + 1.0f);
}

// pack two f32 -> one dword of 2 bf16 (truncation) via v_perm_b32
__device__ __forceinline__ unsigned pk2(float lo, float hi) {
    return __builtin_amdgcn_perm(__builtin_bit_cast(unsigned, hi),
                                 __builtin_bit_cast(unsigned, lo), 0x07060302u);
}

__device__ __forceinline__ bf16x8 pack8(float4 a, float4 b) {
    u32x4 u;
    u[0] = pk2(a.x, a.y); u[1] = pk2(a.z, a.w);
    u[2] = pk2(b.x, b.y); u[3] = pk2(b.z, b.w);
    return __builtin_bit_cast(bf16x8, u);
}

__device__ __forceinline__ float dot4(float4 a, float4 b) {
    float s = a.x * b.x;
    s = fmaf(a.y, b.y, s); s = fmaf(a.z, b.z, s); s = fmaf(a.w, b.w, s);
    return s;
}

// ---- fused per-b wave: hop0 + both hops + sigmoid, f32 direct gathers ----
__global__ __launch_bounds__(256, 2) void ripple_fused(
    const int* __restrict__ users,
    const int* __restrict__ items,
    const int* __restrict__ hop0_items,
    const int* __restrict__ heads,
    const int* __restrict__ relations,
    const int* __restrict__ tails,
    const float* __restrict__ entity_emb,
    const float* __restrict__ relation_emb,
    const float* __restrict__ rec_user_emb,
    const float* __restrict__ rec_item_emb,
    const float* __restrict__ W_ih,
    const float* __restrict__ W_hh,
    const float* __restrict__ b_ih,
    const float* __restrict__ b_hh,
    float* __restrict__ out,
    const int B)
{
    __shared__ __align__(16) unsigned char lds[LDS_WIH + LDS_WHH + LDS_REL + 256];
    unsigned char* wihL = lds;
    unsigned char* whhL = lds + LDS_WIH;
    unsigned char* relL = lds + LDS_WIH + LDS_WHH;
    float* rrL = (float*)(lds + LDS_WIH + LDS_WHH + LDS_REL);

    const int tid = threadIdx.x;

    // ---- stage packed bf16 weight + relation images (per block) ----
    #pragma unroll
    for (int c = 0; c < 4; ++c) {
        int i = tid + 256 * c;              // 0..1023 (W_ih: 32 rows x 32 dwords)
        int row = i >> 5, dw = i & 31;
        *(unsigned*)(wihL + row * WIH_STRIDE + dw * 4) =
            pk2(W_ih[row * 64 + 2 * dw], W_ih[row * 64 + 2 * dw + 1]);
    }
    #pragma unroll
    for (int c = 0; c < 2; ++c) {
        int i = tid + 256 * c;              // 0..511 (W_hh: 32 rows x 16 dwords)
        int row = i >> 4, dw = i & 15;
        *(unsigned*)(whhL + row * WHH_STRIDE + dw * 4) =
            pk2(W_hh[row * 32 + 2 * dw], W_hh[row * 32 + 2 * dw + 1]);
    }
    #pragma unroll
    for (int c = 0; c < 4; ++c) {
        int i = tid + 256 * c;              // 0..1023 (rel: 64 rows x 16 dwords)
        int row = i >> 4, dw = i & 15;
        *(unsigned*)(relL + row * REL_STRIDE + dw * 4) =
            pk2(relation_emb[row * 32 + 2 * dw], relation_emb[row * 32 + 2 * dw + 1]);
    }
    if (tid < 64) {                          // rr[r] = r . r (exact f32)
        float s = 0.0f;
        #pragma unroll
        for (int e = 0; e < DIM; ++e) {
            float v = relation_emb[tid * DIM + e];
            s = fmaf(v, v, s);
        }
        rrL[tid] = s;
    }
    __syncthreads();

    const int wv   = tid >> 6;
    const int lane = tid & 63;
    const int h5   = lane >> 5;
    const int p    = lane & 31;
    const int bb_  = blockIdx.x * WPB + wv;
    if (bb_ >= B) return;
    const int b = __builtin_amdgcn_readfirstlane(bb_);

    // ---- ALL index loads upfront (coalesced) ----
    const int i0A = hop0_items[b * KK + p];
    const int i0B = hop0_items[b * KK + 32 + p];
    int ihA[2], ihB[2], irA[2], irB[2], itA[2], itB[2];
    #pragma unroll
    for (int l = 0; l < 2; ++l) {
        const int base = (l * B + b) * KK;
        ihA[l] = heads[base + p];     ihB[l] = heads[base + 32 + p];
        irA[l] = relations[base + p]; irB[l] = relations[base + 32 + p];
        itA[l] = tails[base + p];     itB[l] = tails[base + 32 + p];
    }

    // ---- uniform q, bias (s_load) + user.q ----
    const int it = __builtin_amdgcn_readfirstlane(items[b]);
    const int uu = __builtin_amdgcn_readfirstlane(users[b]);
    float qu[DIM], bu[DIM];
    #pragma unroll
    for (int d = 0; d < DIM; ++d) {
        qu[d] = entity_emb[(size_t)it * DIM + d] + rec_item_emb[(size_t)it * DIM + d];
        bu[d] = b_ih[d] + b_hh[d];
    }
    float up = 0.0f;
    #pragma unroll
    for (int d = 0; d < DIM; ++d)
        up = fmaf(rec_user_emb[(size_t)uu * DIM + d], qu[d], up);

    // lane-selected views (static indices, cndmask from SGPR)
    float qfa[8], qfb[8];                    // elems [8h5+j], [16+8h5+j]
    #pragma unroll
    for (int j = 0; j < 8; ++j) {
        qfa[j] = h5 ? qu[8 + j]  : qu[j];
        qfb[j] = h5 ? qu[24 + j] : qu[16 + j];
    }
    float qf[16], bv[16];                    // C/D-layout rows d = 8Q + 4h5 + j
    #pragma unroll
    for (int Q = 0; Q < 4; ++Q)
        #pragma unroll
        for (int j = 0; j < 4; ++j) {
            qf[4*Q+j] = h5 ? qu[8*Q + 4 + j] : qu[8*Q + j];
            bv[4*Q+j] = h5 ? bu[8*Q + 4 + j] : bu[8*Q + j];
        }

    // ---- hop-0 dot (paired-lane row gathers) ----
    float part;
    {
        const float* a0  = entity_emb + (size_t)i0A * DIM + 8 * h5;
        const float* b0p = entity_emb + (size_t)i0B * DIM + 8 * h5;
        float4 vA0 = *(const float4*)(a0);      float4 vA1 = *(const float4*)(a0 + 4);
        float4 vA2 = *(const float4*)(a0 + 16); float4 vA3 = *(const float4*)(a0 + 20);
        float4 vB0 = *(const float4*)(b0p);      float4 vB1 = *(const float4*)(b0p + 4);
        float4 vB2 = *(const float4*)(b0p + 16); float4 vB3 = *(const float4*)(b0p + 20);
        float4 c0a = make_float4(qfa[0], qfa[1], qfa[2], qfa[3]);
        float4 c0b = make_float4(qfa[4], qfa[5], qfa[6], qfa[7]);
        float4 c1a = make_float4(qfb[0], qfb[1], qfb[2], qfb[3]);
        float4 c1b = make_float4(qfb[4], qfb[5], qfb[6], qfb[7]);
        part = dot4(vA0, c0a) + dot4(vA1, c0b) + dot4(vA2, c1a) + dot4(vA3, c1b)
             + dot4(vB0, c0a) + dot4(vB1, c0b) + dot4(vB2, c1a) + dot4(vB3, c1b);
    }
    #pragma unroll
    for (int m = 1; m <= 32; m <<= 1) part += __shfl_xor(part, m, 64);

    float tot = part + up;

    // ---- weight frags from block LDS ----
    bf16x8 wihF[4], whhF[2];
    #pragma unroll
    for (int kt = 0; kt < 4; ++kt)
        wihF[kt] = __builtin_bit_cast(bf16x8,
            *(const u32x4*)(wihL + p * WIH_STRIDE + kt * 32 + h5 * 16));
    #pragma unroll
    for (int kt = 0; kt < 2; ++kt)
        whhF[kt] = __builtin_bit_cast(bf16x8,
            *(const u32x4*)(whhL + p * WHH_STRIDE + kt * 32 + h5 * 16));

    // ---- hops ----
    #pragma unroll
    for (int l = 0; l < 2; ++l) {
        // gathers in B-frag layout (2 lanes share each 128B row)
        float4 fh[8], ft[8];
        {
            const float* a = entity_emb + (size_t)ihA[l] * DIM + 8 * h5;
            const float* c = entity_emb + (size_t)ihB[l] * DIM + 8 * h5;
            fh[0] = *(const float4*)(a);      fh[1] = *(const float4*)(a + 4);
            fh[2] = *(const float4*)(a + 16); fh[3] = *(const float4*)(a + 20);
            fh[4] = *(const float4*)(c);      fh[5] = *(const float4*)(c + 4);
            fh[6] = *(const float4*)(c + 16); fh[7] = *(const float4*)(c + 20);
        }
        {
            const float* a = entity_emb + (size_t)itA[l] * DIM + 8 * h5;
            const float* c = entity_emb + (size_t)itB[l] * DIM + 8 * h5;
            ft[0] = *(const float4*)(a);      ft[1] = *(const float4*)(a + 4);
            ft[2] = *(const float4*)(a + 16); ft[3] = *(const float4*)(a + 20);
            ft[4] = *(const float4*)(c);      ft[5] = *(const float4*)(c + 4);
            ft[6] = *(const float4*)(c + 16); ft[7] = *(const float4*)(c + 20);
        }
        float scA = 0.0f, scB = 0.0f;
        #pragma unroll
        for (int i = 0; i < 4; ++i) scA += dot4(fh[i], ft[i]);
        #pragma unroll
        for (int i = 4; i < 8; ++i) scB += dot4(fh[i], ft[i]);

        bf16x8 hfr[2][2], tfr[2][2];
        #pragma unroll
        for (int nt = 0; nt < 2; ++nt)
            #pragma unroll
            for (int kt = 0; kt < 2; ++kt) {
                hfr[nt][kt] = pack8(fh[nt*4 + kt*2], fh[nt*4 + kt*2 + 1]);
                tfr[nt][kt] = pack8(ft[nt*4 + kt*2], ft[nt*4 + kt*2 + 1]);
            }

        // relation frags + rr from LDS
        bf16x8 rfr[2][2];
        #pragma unroll
        for (int kt = 0; kt < 2; ++kt) {
            rfr[0][kt] = __builtin_bit_cast(bf16x8,
                *(const u32x4*)(relL + irA[l] * REL_STRIDE + kt * 32 + h5 * 16));
            rfr[1][kt] = __builtin_bit_cast(bf16x8,
                *(const u32x4*)(relL + irB[l] * REL_STRIDE + kt * 32 + h5 * 16));
        }
        const float rrA = rrL[irA[l]];
        const float rrB = rrL[irB[l]];

        // ---- MFMA chain ----
        f32x16 accA[2], accB[2];
        {
            f32x16 bias_v;
            #pragma unroll
            for (int j = 0; j < 16; ++j) bias_v[j] = bv[j];
            accA[0] = bias_v; accA[1] = bias_v;
        }
        #pragma unroll
        for (int nt = 0; nt < 2; ++nt)
            #pragma unroll
            for (int kt = 0; kt < 2; ++kt)
                accA[nt] = __builtin_amdgcn_mfma_f32_32x32x16_bf16(
                    wihF[2 + kt], rfr[nt][kt], accA[nt], 0, 0, 0);     // C_r
        accB[0] = accA[0]; accB[1] = accA[1];
        #pragma unroll
        for (int nt = 0; nt < 2; ++nt)
            #pragma unroll
            for (int kt = 0; kt < 2; ++kt)
                accB[nt] = __builtin_amdgcn_mfma_f32_32x32x16_bf16(
                    wihF[kt], hfr[nt][kt], accB[nt], 0, 0, 0);         // SH
        #pragma unroll
        for (int nt = 0; nt < 2; ++nt)
            #pragma unroll
            for (int kt = 0; kt < 2; ++kt)
                accA[nt] = __builtin_amdgcn_mfma_f32_32x32x16_bf16(
                    wihF[kt], tfr[nt][kt], accA[nt], 0, 0, 0);         // ST

        // h1 = tanh(SH): in-register C/D -> B-frag transpose via shfl_xor(32)
        unsigned dwA[2][4], dwB[2][4];
        #pragma unroll
        for (int nt = 0; nt < 2; ++nt)
            #pragma unroll
            for (int Q = 0; Q < 4; ++Q) {
                dwA[nt][Q] = pk2(tanh_fast(accB[nt][4*Q+0]), tanh_fast(accB[nt][4*Q+1]));
                dwB[nt][Q] = pk2(tanh_fast(accB[nt][4*Q+2]), tanh_fast(accB[nt][4*Q+3]));
            }
        #pragma unroll
        for (int nt = 0; nt < 2; ++nt)
            #pragma unroll
            for (int kt = 0; kt < 2; ++kt) {
                const unsigned ownA = h5 ? dwA[nt][2*kt+1] : dwA[nt][2*kt];
                const unsigned ownB = h5 ? dwB[nt][2*kt+1] : dwB[nt][2*kt];
                const unsigned sndA = h5 ? dwA[nt][2*kt]   : dwA[nt][2*kt+1];
                const unsigned sndB = h5 ? dwB[nt][2*kt]   : dwB[nt][2*kt+1];
                const unsigned rcvA = __shfl_xor(sndA, 32, 64);
                const unsigned rcvB = __shfl_xor(sndB, 32, 64);
                u32x4 u;
                u[0] = h5 ? rcvA : ownA;
                u[1] = h5 ? rcvB : ownB;
                u[2] = h5 ? ownA : rcvA;
                u[3] = h5 ? ownB : rcvB;
                accA[nt] = __builtin_amdgcn_mfma_f32_32x32x16_bf16(
                    whhF[kt], __builtin_bit_cast(bf16x8, u), accA[nt], 0, 0, 0);  // PRE
            }

        // h2 = tanh(PRE); dots; softmax-weighted sum
        float sA = scA + __shfl_xor(scA, 32, 64);
        float sB = scB + __shfl_xor(scB, 32, 64);
        const float e0 = __expf(sA + rrA);
        const float e1 = __expf(sB + rrB);

        float sd0 = 0.0f, sd1 = 0.0f;
        #pragma unroll
        for (int j = 0; j < 16; ++j) sd0 = fmaf(tanh_fast(accA[0][j]), qf[j], sd0);
        #pragma unroll
        for (int j = 0; j < 16; ++j) sd1 = fmaf(tanh_fast(accA[1][j]), qf[j], sd1);
        sd0 += __shfl_xor(sd0, 32, 64);
        sd1 += __shfl_xor(sd1, 32, 64);

        float num = e0 * sd0 + e1 * sd1;
        float den = e0 + e1;
        #pragma unroll
        for (int m = 1; m <= 16; m <<= 1) {
            num += __shfl_xor(num, m, 64);
            den += __shfl_xor(den, m, 64);
        }
        tot += num * rcp_fast(den);
    }

    if (lane == 0) out[b] = rcp_fast(1.0f + __expf(-tot));
}

extern "C" void kernel_launch(void* const* d_in, const int* in_sizes, int n_in,
                              void* d_out, int out_size, void* d_ws, size_t ws_size,
                              hipStream_t stream)
{
    const int* users = (const int*)d_in[0];
    const int* items = (const int*)d_in[1];
    const int* hop0  = (const int*)d_in[2];
    const int* heads = (const int*)d_in[3];
    const int* rels  = (const int*)d_in[4];
    const int* tails = (const int*)d_in[5];
    const float* entity_emb   = (const float*)d_in[6];
    const float* relation_emb = (const float*)d_in[7];
    const float* rec_user_emb = (const float*)d_in[8];
    const float* rec_item_emb = (const float*)d_in[9];
    const float* W_ih = (const float*)d_in[10];
    const float* W_hh = (const float*)d_in[11];
    const float* b_ih = (const float*)d_in[12];
    const float* b_hh = (const float*)d_in[13];
    float* out = (float*)d_out;

    const int B = in_sizes[0];
    const int blocks = (B + WPB - 1) / WPB;
    hipLaunchKernelGGL(ripple_fused, dim3(blocks), dim3(256), 0, stream,
                       users, items, hop0, heads, rels, tails,
                       entity_emb, relation_emb, rec_user_emb, rec_item_emb,
                       W_ih, W_hh, b_ih, b_hh, out, B);
}